// Round 8
// baseline (285.985 us; speedup 1.0000x reference)
//
#include <hip/hip_runtime.h>

// PolyConv: h = sum_k theta[k] * L_sym^k x,  L_sym = I - D^{-1/2} A D^{-1/2}
// N=100000 nodes, E=1600000 edges, F=64 features, 5 theta terms.
//
// Round 8: (1) CSR entries become int2 (src, fp32 weight=dinv[src]) filled by
// a tiny k_wtab pass -> gather loop has ONE streaming 8B load + ONE dependent
// 128B row gather per edge (was: csr -> dinv[s] -> feat[s], two dependent
// random loads); (2) binA drops the LDS sort + per-edge binary search, edges
// scatter directly to global via LDS bucket cursors (runs stay line-dense in
// L2); (3) gcursor zeroing via hipMemsetAsync (launch removed).

constexpr int kF = 64;
constexpr int BSHIFT = 8;             // bucket = dst >> 8  (256 nodes/bucket)
constexpr int NB = 1 << BSHIFT;       // 256 nodes per bucket
constexpr int TILE = 4096;            // edges per phase-A block
constexpr int KMAX = 512;             // array bound for K (=391)

static __device__ __forceinline__ float bfl(unsigned u) {        // low bf16 -> f32
    return __uint_as_float(u << 16);
}
static __device__ __forceinline__ float bfh(unsigned u) {        // high bf16 -> f32
    return __uint_as_float(u & 0xffff0000u);
}
static __device__ __forceinline__ unsigned f2bf(float f) {       // RNE f32 -> bf16
    unsigned u = __float_as_uint(f);
    return (u + 0x7fffu + ((u >> 16) & 1u)) >> 16;
}
static __device__ __forceinline__ unsigned pack2(float a, float b) {
    return f2bf(a) | (f2bf(b) << 16);
}

// Phase A: multisplit edges into K buckets. Hist -> reserve -> direct global
// scatter with LDS cursors (per-block per-bucket runs ~10 slots, L2 combines).
// Also converts a disjoint slice of x (fp32) -> xb (bf16).
__global__ void k_binA(const int* __restrict__ src, const int* __restrict__ dst,
                       unsigned* __restrict__ pairs, int* __restrict__ gcursor,
                       const float4* __restrict__ x4, uint4* __restrict__ xb4,
                       int n8, int E, int K, int cap) {
    __shared__ int hist[KMAX];
    __shared__ int gb[KMAX];
    const int tid = threadIdx.x;        // blockDim = 512
    const long long tb = (long long)blockIdx.x * TILE;
    const int tcount = (int)min((long long)TILE, (long long)E - tb);

    // fused x -> bf16 convert (disjoint slice per block)
    {
        int per = (n8 + gridDim.x - 1) / (int)gridDim.x;
        int b0 = blockIdx.x * per;
        int b1 = min(b0 + per, n8);
        for (int i = b0 + tid; i < b1; i += 512) {
            float4 a = x4[2 * i];
            float4 b = x4[2 * i + 1];
            uint4 o;
            o.x = pack2(a.x, a.y);
            o.y = pack2(a.z, a.w);
            o.z = pack2(b.x, b.y);
            o.w = pack2(b.z, b.w);
            xb4[i] = o;
        }
    }

    hist[tid] = 0;
    __syncthreads();
    for (int i = tid; i < tcount; i += 512)
        atomicAdd(&hist[dst[tb + i] >> BSHIFT], 1);
    __syncthreads();
    int hv = hist[tid];
    gb[tid] = (tid < K && hv > 0) ? atomicAdd(&gcursor[tid], hv) : 0;
    hist[tid] = 0;                       // reuse as local cursor
    __syncthreads();
    for (int i = tid; i < tcount; i += 512) {
        int d = dst[tb + i];
        int s = src[tb + i];
        int b = d >> BSHIFT;
        int pos = atomicAdd(&hist[b], 1);
        pairs[(size_t)b * cap + gb[b] + pos] =
            ((unsigned)(d & (NB - 1)) << 23) | (unsigned)s;
    }
}

// Phase B: one block (512 threads) per bucket of 256 nodes (K=391 blocks).
// In-kernel gbase scan, per-node counts -> LDS scan -> scatter src into
// ecsr[].x (bucket region ~32KB, L2-resident), emits rp + dinv.
__global__ void k_binB(const unsigned* __restrict__ pairs, const int* __restrict__ gcursor,
                       int* __restrict__ rp, float* __restrict__ dinv,
                       int2* __restrict__ ecsr, int N, int E, int K, int cap) {
    __shared__ int gsc[KMAX];
    __shared__ int cnt[NB];
    __shared__ int stmp[NB];
    __shared__ int excl[NB];
    __shared__ int cur[NB];
    const int b = blockIdx.x;
    const int tid = threadIdx.x;        // blockDim = 512

    int gv = (tid < K) ? gcursor[tid] : 0;
    gsc[tid] = gv;
    __syncthreads();
    for (int o = 1; o < KMAX; o <<= 1) {
        int t = (tid >= o) ? gsc[tid - o] : 0;
        __syncthreads();
        gsc[tid] += t;
        __syncthreads();
    }
    const int ecnt = gcursor[b];
    const int base = gsc[b] - ecnt;     // inclusive - own = exclusive
    const unsigned* bp = pairs + (size_t)b * cap;

    if (tid < NB) cnt[tid] = 0;
    __syncthreads();
    for (int i = tid; i < ecnt; i += 512)
        atomicAdd(&cnt[bp[i] >> 23], 1);
    __syncthreads();
    int v = (tid < NB) ? cnt[tid] : 0;
    if (tid < NB) stmp[tid] = v;
    __syncthreads();
    for (int o = 1; o < NB; o <<= 1) {
        int t = (tid >= o && tid < NB) ? stmp[tid - o] : 0;
        __syncthreads();
        if (tid < NB) stmp[tid] += t;
        __syncthreads();
    }
    if (tid < NB) {
        excl[tid] = stmp[tid] - v;
        cur[tid] = stmp[tid] - v;
    }
    __syncthreads();
    for (int i = tid; i < ecnt; i += 512) {
        unsigned p = bp[i];
        int pos = atomicAdd(&cur[p >> 23], 1);
        ecsr[base + pos].x = (int)(p & 0x7FFFFFu);
    }
    int node = (b << BSHIFT) + tid;
    if (tid < NB && node < N) {
        rp[node] = base + excl[tid];
        dinv[node] = rsqrtf(fmaxf((float)v, 1.0f));
    }
    if (b == K - 1 && tid == 0) rp[N] = E;
}

// Fill per-edge weight: ecsr[e].y = bits(dinv[ecsr[e].x]).
// dinv table is 400KB (L2-hot); read/write 8B coalesced.
__global__ void k_wtab(int2* __restrict__ ecsr, const float* __restrict__ dinv, int E) {
    int e = blockIdx.x * blockDim.x + threadIdx.x;
    if (e < E) {
        int2 v = ecsr[e];
        v.y = __float_as_int(dinv[v.x]);
        ecsr[e] = v;
    }
}

// TWO nodes per wave, bf16 feature table (128B rows), K-loop unrolled x2.
// Lane l: half = l>>5, r = (l>>3)&3, c = l&7 (16B = 8 features).
// Per edge: one streaming 8B (src,w) load + one dependent 128B row gather.
// Butterfly over lanes ^8,^16 leaves lanes {0..7, 32..39} complete.
template <bool FIRST, bool LAST>
__global__ void k_gather(const int* __restrict__ rp, const int2* __restrict__ ecsr,
                         const unsigned short* __restrict__ featin,
                         const float* __restrict__ xf,
                         const float* __restrict__ dinv,
                         unsigned short* __restrict__ featout,
                         float* __restrict__ h,
                         int n, float th0, float theta) {
    int wid = (blockIdx.x * blockDim.x + threadIdx.x) >> 6;
    int lane = threadIdx.x & 63;
    int half = lane >> 5;
    int r = (lane >> 3) & 3;
    int c = lane & 7;
    int node = wid * 2 + half;
    if (wid * 2 >= n) return;
    bool valid = node < n;
    int beg = valid ? rp[node] : 0;
    int end = valid ? rp[node + 1] : 0;
    int len = end - beg;
    int olen = __shfl_xor(len, 32, 64);
    int mlen = (len > olen) ? len : olen;   // pair max -> uniform trip count

    float acc[8] = {0.f, 0.f, 0.f, 0.f, 0.f, 0.f, 0.f, 0.f};
    for (int i = 0; i < mlen; i += 8) {
        int j1 = beg + i + r;
        int j2 = j1 + 4;
        bool ok1 = j1 < end;
        bool ok2 = j2 < end;
        int2 e1 = ecsr[ok1 ? j1 : 0];
        int2 e2 = ecsr[ok2 ? j2 : 0];
        int s1 = e1.x;
        int s2 = e2.x;
        float w1 = ok1 ? __int_as_float(e1.y) : 0.0f;
        float w2 = ok2 ? __int_as_float(e2.y) : 0.0f;
        uint4 ra = *(const uint4*)(featin + ((size_t)s1 << 6) + (c << 3));
        uint4 rb = *(const uint4*)(featin + ((size_t)s2 << 6) + (c << 3));
        acc[0] += w1 * bfl(ra.x);
        acc[1] += w1 * bfh(ra.x);
        acc[2] += w1 * bfl(ra.y);
        acc[3] += w1 * bfh(ra.y);
        acc[4] += w1 * bfl(ra.z);
        acc[5] += w1 * bfh(ra.z);
        acc[6] += w1 * bfl(ra.w);
        acc[7] += w1 * bfh(ra.w);
        acc[0] += w2 * bfl(rb.x);
        acc[1] += w2 * bfh(rb.x);
        acc[2] += w2 * bfl(rb.y);
        acc[3] += w2 * bfh(rb.y);
        acc[4] += w2 * bfl(rb.z);
        acc[5] += w2 * bfh(rb.z);
        acc[6] += w2 * bfl(rb.w);
        acc[7] += w2 * bfh(rb.w);
    }
    #pragma unroll
    for (int m = 8; m <= 16; m <<= 1) {
        #pragma unroll
        for (int i = 0; i < 8; ++i)
            acc[i] += __shfl_xor(acc[i], m, 64);
    }

    if (r == 0 && valid) {                   // lanes 0..7 and 32..39
        size_t off = ((size_t)node << 6) + (c << 3);
        float f[8];
        if (FIRST) {
            float4 a = *(const float4*)(xf + off);
            float4 b = *(const float4*)(xf + off + 4);
            f[0] = a.x; f[1] = a.y; f[2] = a.z; f[3] = a.w;
            f[4] = b.x; f[5] = b.y; f[6] = b.z; f[7] = b.w;
        } else {
            uint4 rr = *(const uint4*)(featin + off);
            f[0] = bfl(rr.x); f[1] = bfh(rr.x);
            f[2] = bfl(rr.y); f[3] = bfh(rr.y);
            f[4] = bfl(rr.z); f[5] = bfh(rr.z);
            f[6] = bfl(rr.w); f[7] = bfh(rr.w);
        }
        float di = dinv[node];
        float v[8];
        #pragma unroll
        for (int i = 0; i < 8; ++i) v[i] = f[i] - di * acc[i];
        float4 h0, h1;
        if (FIRST) {
            h0 = make_float4(th0 * f[0] + theta * v[0], th0 * f[1] + theta * v[1],
                             th0 * f[2] + theta * v[2], th0 * f[3] + theta * v[3]);
            h1 = make_float4(th0 * f[4] + theta * v[4], th0 * f[5] + theta * v[5],
                             th0 * f[6] + theta * v[6], th0 * f[7] + theta * v[7]);
        } else {
            h0 = *(const float4*)(h + off);
            h1 = *(const float4*)(h + off + 4);
            h0.x += theta * v[0]; h0.y += theta * v[1];
            h0.z += theta * v[2]; h0.w += theta * v[3];
            h1.x += theta * v[4]; h1.y += theta * v[5];
            h1.z += theta * v[6]; h1.w += theta * v[7];
        }
        *(float4*)(h + off) = h0;
        *(float4*)(h + off + 4) = h1;
        if (!LAST) {
            uint4 o;
            o.x = pack2(v[0], v[1]);
            o.y = pack2(v[2], v[3]);
            o.z = pack2(v[4], v[5]);
            o.w = pack2(v[6], v[7]);
            *(uint4*)(featout + off) = o;
        }
    }
}

extern "C" void kernel_launch(void* const* d_in, const int* in_sizes, int n_in,
                              void* d_out, int out_size, void* d_ws, size_t ws_size,
                              hipStream_t stream) {
    const float* x  = (const float*)d_in[0];
    const int*   ei = (const int*)d_in[1];   // edge_index [2, E] row-major
    const int N = in_sizes[0] / kF;
    const int E = in_sizes[1] / 2;
    const int* src = ei;
    const int* dst = ei + E;
    float* h = (float*)d_out;

    const int K = (N + NB - 1) >> BSHIFT;         // 391 buckets (K <= KMAX)
    const int cap = 2 * ((E + K - 1) / K);        // per-bucket capacity

    // workspace (~64 MB): gcursor | rp | dinv | ecsr | xb | featA | featB | pairs
    char* ws = (char*)d_ws;
    size_t off = 0;
    auto carve = [&](size_t bytes) {
        void* p = ws + off;
        off = (off + bytes + 511) & ~(size_t)511;
        return p;
    };
    int*            gcursor = (int*)carve((size_t)K * 4);
    int*            rp      = (int*)carve((size_t)(N + 1) * 4);
    float*          dinv    = (float*)carve((size_t)N * 4);
    int2*           ecsr    = (int2*)carve((size_t)E * 8);
    unsigned short* xb      = (unsigned short*)carve((size_t)N * kF * 2);
    unsigned short* featA   = (unsigned short*)carve((size_t)N * kF * 2);
    unsigned short* featB   = (unsigned short*)carve((size_t)N * kF * 2);
    unsigned*       pairs   = (unsigned*)carve((size_t)K * cap * 4);

    const float theta[5] = {0.6f, -0.4f, 0.3f, -0.2f, 0.1f};

    // ---- CSR build (multisplit) with fused x->bf16 convert ----
    const int n8 = N * kF / 8;
    hipMemsetAsync(gcursor, 0, (size_t)K * 4, stream);
    k_binA<<<(E + TILE - 1) / TILE, 512, 0, stream>>>(src, dst, pairs, gcursor,
                                                      (const float4*)x, (uint4*)xb,
                                                      n8, E, K, cap);
    k_binB<<<K, 512, 0, stream>>>(pairs, gcursor, rp, dinv, ecsr, N, E, K, cap);
    k_wtab<<<(E + 511) / 512, 512, 0, stream>>>(ecsr, dinv, E);

    // ---- 4 fused gather+update passes (k=1 also does init), ping-pong ----
    const int nwaves = (N + 1) / 2;                // 2 nodes per wave
    const int gblocks = (nwaves + 3) / 4;          // 4 waves per 256-thread block
    k_gather<true, false><<<gblocks, 256, 0, stream>>>(rp, ecsr, xb, x, dinv, featA, h,
                                                       N, theta[0], theta[1]);
    k_gather<false, false><<<gblocks, 256, 0, stream>>>(rp, ecsr, featA, nullptr, dinv, featB, h,
                                                        N, 0.f, theta[2]);
    k_gather<false, false><<<gblocks, 256, 0, stream>>>(rp, ecsr, featB, nullptr, dinv, featA, h,
                                                        N, 0.f, theta[3]);
    k_gather<false, true><<<gblocks, 256, 0, stream>>>(rp, ecsr, featA, nullptr, dinv, nullptr, h,
                                                       N, 0.f, theta[4]);
}